// Round 1
// baseline (223.121 us; speedup 1.0000x reference)
//
#include <hip/hip_runtime.h>
#include <math.h>

// pix_attn: B = 8*64*64 pixels, C=64, 8 heads x d=8, 9 window tokens (scrambled
// torch layout) + pooled-global token + q·q_ logit, output proj 64x64.
//
// Layout facts used (verified against the reference):
//  - xs[p,t,c] = window[ch=(t*64+c)/9, l=(t*64+c)%9], l=(i*3+j), value =
//    x[b, ch, reflect(h+i-1), reflect(w+j-1)]
//  - qk cols: q = o in [0,64) -> o = h*8+d ; q_ = 64 + h*8 + d
//  - kv cols: k = h*8+d ; v = 64 + h*8 + d   (reshape (B,N,2,8,8))
//  - global token k_g = mean_l k_l (bias folds through the mean)
//  - logits order irrelevant for softmax: tokens 1..9, then global, then qv.

__global__ __launch_bounds__(256, 2) void pix_attn_main(
    const float* __restrict__ x,
    const float* __restrict__ W_qk,
    const float* __restrict__ b_qk,
    const float* __restrict__ W_kv,
    const float* __restrict__ b_kv,
    const float* __restrict__ W_proj,
    const float* __restrict__ b_proj,
    float* __restrict__ out)
{
    __shared__ float xt[6400];        // [ch][10][10] halo tile
    __shared__ float pre_s[64 * 65];  // [pixel][64ch], pad->stride 65 (bank-free)
    __shared__ int   aoff[576];       // scramble table: f -> ch*100 + wi*10 + wj

    const int tid  = threadIdx.x;
    const int blk  = blockIdx.x;
    const int bb   = blk >> 6;
    const int t_id = blk & 63;
    const int h0   = (t_id >> 3) << 3;
    const int w0   = (t_id & 7) << 3;

    // scramble-offset table (uniform data, broadcast-read later)
    for (int f = tid; f < 576; f += 256) {
        int sc = f / 9;
        int wl = f - sc * 9;
        int wi = wl / 3;
        int wj = wl - wi * 3;
        aoff[f] = sc * 100 + wi * 10 + wj;
    }

    // stage x tile with reflect halo
    const float* xb = x + (size_t)bb * (64 * 64 * 64);
    for (int idx = tid; idx < 6400; idx += 256) {
        int ch  = idx / 100;
        int rem = idx - ch * 100;
        int r   = rem / 10;
        int cc  = rem - r * 10;
        int gr  = h0 + r - 1;
        gr = (gr < 0) ? 1 : ((gr > 63) ? 62 : gr);
        int gc  = w0 + cc - 1;
        gc = (gc < 0) ? 1 : ((gc > 63) ? 62 : gc);
        xt[idx] = xb[(ch << 12) + (gr << 6) + gc];
    }
    __syncthreads();

    const int wave = __builtin_amdgcn_readfirstlane(tid >> 6);
    const int lane = tid & 63;
    const int tr   = lane >> 3;
    const int tc   = lane & 7;
    const int lofs = tr * 10 + tc;
    const float scale = 0.35355339059327373f;  // 8^-0.5

    for (int hh = 0; hh < 2; ++hh) {
        const int h = wave * 2 + hh;  // wave-uniform -> scalar weight loads

        // ---- q / q_ projection (center pixel) ----
        float q[8], qp[8];
#pragma unroll
        for (int d = 0; d < 8; ++d) {
            q[d]  = b_qk[h * 8 + d];
            qp[d] = b_qk[64 + h * 8 + d];
        }
#pragma unroll
        for (int c = 0; c < 64; ++c) {
            float a = xt[c * 100 + 11 + lofs];
            const float* w = W_qk + (c << 7) + (h << 3);
#pragma unroll
            for (int d = 0; d < 8; ++d) {
                q[d]  = fmaf(a, w[d], q[d]);
                qp[d] = fmaf(a, w[64 + d], qp[d]);
            }
        }
        float qv = 0.f;
#pragma unroll
        for (int d = 0; d < 8; ++d) qv = fmaf(q[d], qp[d], qv);

        // ---- tokens with online softmax ----
        float m = -1e30f, s = 0.f;
        float oacc[8], ksum[8], vsum[8];
#pragma unroll
        for (int d = 0; d < 8; ++d) { oacc[d] = 0.f; ksum[d] = 0.f; vsum[d] = 0.f; }

        float bk[8], bv[8];
#pragma unroll
        for (int d = 0; d < 8; ++d) {
            bk[d] = b_kv[h * 8 + d];
            bv[d] = b_kv[64 + h * 8 + d];
        }

#pragma unroll 1
        for (int t = 0; t < 9; ++t) {
            float k[8], v[8];
#pragma unroll
            for (int d = 0; d < 8; ++d) { k[d] = bk[d]; v[d] = bv[d]; }
#pragma unroll
            for (int c = 0; c < 64; ++c) {
                int   ao = aoff[t * 64 + c];   // uniform broadcast read
                float a  = xt[ao + lofs];
                const float* w = W_kv + (c << 7) + (h << 3);
#pragma unroll
                for (int d = 0; d < 8; ++d) {
                    k[d] = fmaf(a, w[d], k[d]);
                    v[d] = fmaf(a, w[64 + d], v[d]);
                }
            }
            float lg = 0.f;
#pragma unroll
            for (int d = 0; d < 8; ++d) {
                lg = fmaf(q[d], k[d], lg);
                ksum[d] += k[d];
                vsum[d] += v[d];
            }
            lg *= scale;
            float mn   = fmaxf(m, lg);
            float corr = __expf(m - mn);
            float p    = __expf(lg - mn);
            s = s * corr + p;
#pragma unroll
            for (int d = 0; d < 8; ++d) oacc[d] = fmaf(oacc[d], corr, p * v[d]);
            m = mn;
        }

        // pooled-global token: k_g = ksum/9, v_g = vsum/9
        {
            float lg = 0.f;
#pragma unroll
            for (int d = 0; d < 8; ++d) lg = fmaf(q[d], ksum[d] * (1.f / 9.f), lg);
            lg *= scale;
            float mn   = fmaxf(m, lg);
            float corr = __expf(m - mn);
            float p    = __expf(lg - mn);
            s = s * corr + p;
#pragma unroll
            for (int d = 0; d < 8; ++d)
                oacc[d] = fmaf(oacc[d], corr, p * (vsum[d] * (1.f / 9.f)));
            m = mn;
        }

        // q_value logit, value vector = q_
        {
            float lg   = qv;
            float mn   = fmaxf(m, lg);
            float corr = __expf(m - mn);
            float p    = __expf(lg - mn);
            s = s * corr + p;
#pragma unroll
            for (int d = 0; d < 8; ++d) oacc[d] = fmaf(oacc[d], corr, p * qp[d]);
            m = mn;
        }

        float inv = 1.f / s;
#pragma unroll
        for (int d = 0; d < 8; ++d)
            pre_s[lane * 65 + h * 8 + d] = oacc[d] * inv;
    }
    __syncthreads();

    // ---- output projection: this pixel, 16 channels per thread ----
    const int j0 = wave << 4;
    float o[16];
#pragma unroll
    for (int j = 0; j < 16; ++j) o[j] = b_proj[j0 + j];
#pragma unroll
    for (int c = 0; c < 64; ++c) {
        float a = pre_s[lane * 65 + c];
        const float* w = W_proj + (c << 6) + j0;
#pragma unroll
        for (int j = 0; j < 16; ++j) o[j] = fmaf(a, w[j], o[j]);
    }
    float* ob = out + (size_t)bb * (64 * 64 * 64);
    const int pr = h0 + tr, pc = w0 + tc;
#pragma unroll
    for (int j = 0; j < 16; ++j)
        ob[((j0 + j) << 12) + (pr << 6) + pc] = o[j];
}

extern "C" void kernel_launch(void* const* d_in, const int* in_sizes, int n_in,
                              void* d_out, int out_size, void* d_ws, size_t ws_size,
                              hipStream_t stream)
{
    const float* x      = (const float*)d_in[0];
    const float* W_qk   = (const float*)d_in[1];
    const float* b_qk   = (const float*)d_in[2];
    const float* W_kv   = (const float*)d_in[3];
    const float* b_kv   = (const float*)d_in[4];
    const float* W_proj = (const float*)d_in[5];
    const float* b_proj = (const float*)d_in[6];
    float* out = (float*)d_out;

    pix_attn_main<<<512, 256, 0, stream>>>(x, W_qk, b_qk, W_kv, b_kv,
                                           W_proj, b_proj, out);
}